// Round 19
// baseline (79.945 us; speedup 1.0000x reference)
//
#include <hip/hip_runtime.h>
#include <hip/hip_bf16.h>

// FirDownsample: y = depthwise FIR(4x4 separable [1,3,3,1]) on x (pad 2),
// out = conv3x3(y, w), stride 2.  x:(16,320,64,64) f32, out:(16,320,32,32) f32.
//
// R19 = R18 with GENERIC edge zeroing (R18 missed band 15's t=6 -> xrow=64):
// slot t valid iff 0 <= r0+t-2 <= 63; zero t < max(0,2-r0) and t >= 66-r0.
// fir: async global_load_lds staging of x window (high MLP), vert from x_lds,
// horiz -> 16B stores. conv, wt2 byte-identical to R10.
//   K1 fir_kernel : x -> y[n][cc=10][65][65][32ci] bf16
//   K2 wt2_kernel : w -> wt2[tap][cc][q][co][8ci] bf16
//   K3 conv_kernel: M64xN64 block, 4 waves M64xN16, B reg-dbuf, A via global_load_lds.

typedef short bf16x8_t __attribute__((ext_vector_type(8)));
typedef float f32x4 __attribute__((ext_vector_type(4)));
typedef unsigned int u32x4 __attribute__((ext_vector_type(4)));
typedef __attribute__((address_space(1))) const unsigned int* as1_u32p;
typedef __attribute__((address_space(3))) unsigned int* as3_u32p;

#define NI 16
#define CCH 320
#define HW 64
#define HY 65
#define HY2 4225           // 65*65
#define CCSTEP 135200      // 4225*32 shorts per cc-plane

__device__ __forceinline__ float bf16lo(unsigned int u) {
    return __uint_as_float(u << 16);
}
__device__ __forceinline__ float bf16hi(unsigned int u) {
    return __uint_as_float(u & 0xffff0000u);
}

// ---------------- K1: separable FIR, x(f32) -> y bf16 [n][cc][r][c][32] ----------------
// block = (n, 4-row band, 16-ci group). Phase 0: async-stage x window into LDS
// (7 x 1KB/wave issues), then zero invalid row slots. Phase 1: vert from x_lds.
// Phase 2: horiz -> 16B stores.
__global__ __launch_bounds__(256) void fir_kernel(const float* __restrict__ x,
                                                  const float* __restrict__ fir_k,
                                                  __hip_bfloat16* __restrict__ yt) {
    __shared__ float xls[7 * 16 * 64];            // 28,672 B  [t][ci16][w64]
    __shared__ unsigned short vlds[4 * 16 * 70];  //  8,960 B  [j][ci16][70]

    int bx = blockIdx.x;
    int n    = bx / 340;
    int rem  = bx % 340;
    int band = rem / 20;          // 0..16
    int cig  = rem % 20;          // 16-ci group
    int r0   = band * 4;

    float f0 = fir_k[0] + fir_k[1] + fir_k[2] + fir_k[3];
    float f1 = fir_k[4] + fir_k[5] + fir_k[6] + fir_k[7];
    float f2 = fir_k[8] + fir_k[9] + fir_k[10] + fir_k[11];
    float f3 = fir_k[12] + fir_k[13] + fir_k[14] + fir_k[15];

    int tid = threadIdx.x;
    int lane = tid & 63;
    int g = tid >> 6;

    // ---- Phase 0: async stage x[7 rows][16 ci][64 w] (clamped rows) ----
    const unsigned int* xb = (const unsigned int*)(x + (size_t)(n * CCH + cig * 16) * (HW * HW));
#pragma unroll
    for (int k = 0; k < 7; ++k) {
        int l16 = k * 256 + tid;          // 0..1791 16B-lanes
        int t   = l16 >> 8;               // row slot 0..6 (256 lanes per row)
        int rm  = l16 & 255;
        int ci  = rm >> 4;                // 0..15
        int w4  = (rm & 15) * 4;          // f32 col
        int xrow = r0 + t - 2;
        int xr = xrow < 0 ? 0 : (xrow > 63 ? 63 : xrow);
        __builtin_amdgcn_global_load_lds(
            (as1_u32p)(xb + (size_t)ci * 4096 + xr * 64 + w4),
            (as3_u32p)((unsigned int*)xls + (size_t)l16 * 4), 16, 0, 0);
    }
    __syncthreads();   // drains vmcnt: x_lds ready

    // ---- generic edge zeroing: slot t valid iff 0 <= r0+t-2 <= 63 ----
    {
        int t_lo = 2 - r0;  if (t_lo < 0) t_lo = 0;   // zero t in [0, t_lo)
        int t_hi = 66 - r0; if (t_hi > 7) t_hi = 7;   // zero t in [t_hi, 7)
        if (t_lo > 0 || t_hi < 7) {
            f32x4 z = (f32x4){0.f, 0.f, 0.f, 0.f};
            for (int t = 0; t < t_lo; ++t)
                ((f32x4*)(xls + t * 1024))[tid] = z;      // 256 f32x4 per slot
            for (int t = t_hi; t < 7; ++t)
                ((f32x4*)(xls + t * 1024))[tid] = z;
            __syncthreads();
        }
    }

    // ---- Phase 1: vertical pass. wave g covers cis g*4..g*4+3, lane = w ----
#pragma unroll
    for (int m = 0; m < 16; ++m) {
        int j   = m >> 2;
        int cis = g * 4 + (m & 3);
        int base = cis * 64 + lane;
        float v = f0 * xls[j * 1024 + base] + f1 * xls[(j + 1) * 1024 + base]
                + f2 * xls[(j + 2) * 1024 + base] + f3 * xls[(j + 3) * 1024 + base];
        vlds[(j * 16 + cis) * 70 + lane + 2] = __bfloat16_as_ushort(__float2bfloat16(v));
    }
    // pad columns 0,1 and 66,67 (wave 0; u32 zero writes)
    if (g == 0) {
        unsigned int* vp = (unsigned int*)vlds + (size_t)lane * 35;
        vp[0] = 0; vp[33] = 0;
    }
    __syncthreads();

    // ---- Phase 2: horizontal pass: task = (j, pp, oct s in 0..1); 264 tasks ----
    unsigned short* yu = (unsigned short*)yt;
    int cc = cig >> 1;
    int O  = (cig & 1) * 2;
    size_t plane = (size_t)(n * 10 + cc) * HY2;
#pragma unroll
    for (int it = 0; it < 2; ++it) {
        int task = it * 256 + tid;
        if (task < 264) {
            int s  = task & 1;
            int t2 = task >> 1;          // 0..131
            int j  = t2 / 33;
            int pp = t2 % 33;
            int c  = 2 * pp;
            int r  = r0 + j;
            if (r < HY) {
                bool pair = (pp < 32);
                float a0[8], a1[8];
#pragma unroll
                for (int k = 0; k < 8; ++k) {
                    const unsigned int* vp =
                        (const unsigned int*)(vlds + (size_t)(j * 16 + s * 8 + k) * 70 + c);
                    unsigned int u0 = vp[0], u1 = vp[1];
                    float v0 = bf16lo(u0), v1 = bf16hi(u0);
                    float v2 = bf16lo(u1), v3 = bf16hi(u1);
                    a0[k] = f0 * v0 + f1 * v1 + f2 * v2 + f3 * v3;
                    if (pair) {
                        float v4 = bf16lo(vp[2]);
                        a1[k] = f0 * v1 + f1 * v2 + f2 * v3 + f3 * v4;
                    }
                }
                unsigned int w0[4];
#pragma unroll
                for (int h = 0; h < 4; ++h) {
                    unsigned int lo = __bfloat16_as_ushort(__float2bfloat16(a0[2 * h]));
                    unsigned int hi = __bfloat16_as_ushort(__float2bfloat16(a0[2 * h + 1]));
                    w0[h] = lo | (hi << 16);
                }
                size_t base = (plane + (size_t)r * HY + c) * 32 + (O + s) * 8;
                *(u32x4*)(yu + base) = (u32x4){w0[0], w0[1], w0[2], w0[3]};
                if (pair) {
                    unsigned int w1[4];
#pragma unroll
                    for (int h = 0; h < 4; ++h) {
                        unsigned int lo = __bfloat16_as_ushort(__float2bfloat16(a1[2 * h]));
                        unsigned int hi = __bfloat16_as_ushort(__float2bfloat16(a1[2 * h + 1]));
                        w1[h] = lo | (hi << 16);
                    }
                    *(u32x4*)(yu + base + 32) = (u32x4){w1[0], w1[1], w1[2], w1[3]};
                }
            }
        }
    }
}

// ---------------- K2: w (co,ci,3,3) f32 -> wt2[tap][cc][q][co][8] bf16 ----------------
__global__ __launch_bounds__(256) void wt2_kernel(const float* __restrict__ w,
                                                  __hip_bfloat16* __restrict__ wt) {
    int idx = blockIdx.x * 256 + threadIdx.x;
    if (idx < 9 * CCH * CCH) {
        int j  = idx & 7;
        int co = (idx >> 3) % CCH;
        int t2 = idx / 2560;          // tap*40 + cc*4 + q
        int q  = t2 & 3;
        int cc = (t2 >> 2) % 10;
        int tap = t2 / 40;
        int ci = cc * 32 + q * 8 + j;
        wt[idx] = __float2bfloat16(w[(co * CCH + ci) * 9 + tap]);
    }
}

// ---------------- K3: MFMA conv, M64 x N64, waves M64xN16, B reg-dbuf (exact R10) ----------------
__global__ __launch_bounds__(256, 3) void conv_kernel(const __hip_bfloat16* __restrict__ yt,
                                                      const __hip_bfloat16* __restrict__ wt2,
                                                      float* __restrict__ out) {
    __shared__ short ylds[2][1536 * 8];   // 2 x 24,576 B

    int bx = blockIdx.x;
    int sp = bx & 15;
    int t  = bx >> 4;
    int cb = t % 5;
    int n  = t / 5;
    int co0 = cb * 64;
    int oh0 = (sp >> 1) * 4;
    int ow0 = (sp & 1) * 16;

    int tid = threadIdx.x;
    int lane = tid & 63;
    int wid = tid >> 6;
    int q = lane >> 4, lc = lane & 15;

    const unsigned short* ytu = (const unsigned short*)yt;
    const unsigned short* wtu = (const unsigned short*)wt2;

    // per-lane global source offsets (shorts) for staging units, cc=0
    int ybase = (n * 10 * HY2 + (2 * oh0) * HY + 2 * ow0) * 32;
    int goff[6];
#pragma unroll
    for (int k = 0; k < 6; ++k) {
        int u = k * 256 + tid;
        int uc = (u < 1485) ? u : 1484;    // tail: safe dup, lands in pad units
        int p = uc / 5, s = uc - p * 5;
        if (s == 4) s = 3;                 // row-pad unit: dup of unit 3, never read
        int pr = p / 33, pc = p - pr * 33;
        goff[k] = ybase + (pr * HY + pc) * 32 + s * 8;
    }

    const unsigned short* wbl = wtu + q * 2560 + (size_t)(co0 + wid * 16 + lc) * 8;
    const int aoff = (2 * lc) * 40 + q * 8;   // short-index within buffer

    f32x4 acc[4];
#pragma unroll
    for (int i = 0; i < 4; ++i) acc[i] = (f32x4){0.f, 0.f, 0.f, 0.f};

    bf16x8_t bfr[2][9];

    // wave-uniform LDS unit base for stage issue k: (k*256 + wid*64) units
#define GLDS(buf, K, ccidx)                                                            \
    __builtin_amdgcn_global_load_lds(                                                  \
        (as1_u32p)(ytu + goff[K] + (ccidx) * CCSTEP),                                  \
        (as3_u32p)(&ylds[buf][(size_t)((K) * 256 + wid * 64) * 8]), 16, 0, 0)

    // prologue: stage A(0) -> buf0, load B(0) -> bfr[0]
#pragma unroll
    for (int k = 0; k < 6; ++k) GLDS(0, k, 0);
#pragma unroll
    for (int kk = 0; kk < 9; ++kk)
        bfr[0][kk] = *(const bf16x8_t*)(wbl + kk * 102400);
    __syncthreads();

    auto compute = [&](const short* buf, const bf16x8_t* b) {
#pragma unroll
        for (int kw = 0; kw < 3; ++kw) {
            bf16x8_t af[9];
#pragma unroll
            for (int r = 0; r < 9; ++r)
                af[r] = *(const bf16x8_t*)(buf + aoff + (r * 33 + kw) * 40);
#pragma unroll
            for (int kh = 0; kh < 3; ++kh)
#pragma unroll
                for (int mf = 0; mf < 4; ++mf)
                    acc[mf] = __builtin_amdgcn_mfma_f32_16x16x32_bf16(
                        b[kh * 3 + kw], af[2 * mf + kh], acc[mf], 0, 0, 0);
        }
    };

    for (int tt = 0; tt < 5; ++tt) {
        int cc0 = 2 * tt, cc1 = 2 * tt + 1;
        // ---- even cc: compute from buf0/bfr[0]; prefetch cc0+1 -> buf1/bfr[1]
        {
#pragma unroll
            for (int k = 0; k < 6; ++k) GLDS(1, k, cc0 + 1);
            const unsigned short* wnx = wbl + (cc0 + 1) * 10240;
#pragma unroll
            for (int kk = 0; kk < 9; ++kk)
                bfr[1][kk] = *(const bf16x8_t*)(wnx + kk * 102400);
            compute(&ylds[0][0], bfr[0]);
            __syncthreads();   // drains vmcnt -> A(cc0+1) in LDS, bfr[1] ready
        }
        // ---- odd cc: compute from buf1/bfr[1]; prefetch cc1+1 -> buf0/bfr[0]
        {
            if (cc1 < 9) {
#pragma unroll
                for (int k = 0; k < 6; ++k) GLDS(0, k, cc1 + 1);
                const unsigned short* wnx = wbl + (cc1 + 1) * 10240;
#pragma unroll
                for (int kk = 0; kk < 9; ++kk)
                    bfr[0][kk] = *(const bf16x8_t*)(wnx + kk * 102400);
            }
            compute(&ylds[1][0], bfr[1]);
            if (cc1 < 9) __syncthreads();
        }
    }
#undef GLDS

    // epilogue: D[row=co][col=m]; coalesced 64B segments
#pragma unroll
    for (int mf = 0; mf < 4; ++mf) {
        int oh = oh0 + mf;
        int ow = ow0 + lc;
#pragma unroll
        for (int rg = 0; rg < 4; ++rg) {
            int co = co0 + wid * 16 + q * 4 + rg;
            out[((n * CCH + co) * 32 + oh) * 32 + ow] = acc[mf][rg];
        }
    }
}

// ---------------- Fallback: naive direct (correct, slow) ----------------
__global__ __launch_bounds__(256) void naive_kernel(const float* __restrict__ x,
                                                    const float* __restrict__ w,
                                                    const float* __restrict__ fk,
                                                    float* __restrict__ out) {
    int idx = blockIdx.x * 256 + threadIdx.x;
    if (idx >= NI * CCH * 32 * 32) return;
    int ow = idx & 31;
    int oh = (idx >> 5) & 31;
    int co = (idx >> 10) % CCH;
    int n = (idx >> 10) / CCH;
    float f0 = fk[0] + fk[1] + fk[2] + fk[3];
    float f1 = fk[4] + fk[5] + fk[6] + fk[7];
    float f2 = fk[8] + fk[9] + fk[10] + fk[11];
    float f3 = fk[12] + fk[13] + fk[14] + fk[15];
    float fv[4] = {f0, f1, f2, f3};
    float acc = 0.f;
    for (int ci = 0; ci < CCH; ++ci) {
        const float* xb = x + (size_t)(n * CCH + ci) * HW * HW;
        const float* wb = w + (size_t)(co * CCH + ci) * 9;
#pragma unroll
        for (int u = 0; u < 3; ++u) {
            int yr = 2 * oh + u;
#pragma unroll
            for (int v = 0; v < 3; ++v) {
                int yc = 2 * ow + v;
                float s = 0.f;
#pragma unroll
                for (int a = 0; a < 4; ++a) {
                    int xrw = yr - 2 + a;
                    if (xrw < 0 || xrw >= HW) continue;
                    float t = 0.f;
#pragma unroll
                    for (int b = 0; b < 4; ++b) {
                        int xc = yc - 2 + b;
                        if (xc >= 0 && xc < HW) t += fv[b] * xb[xrw * HW + xc];
                    }
                    s += fv[a] * t;
                }
                acc += wb[u * 3 + v] * s;
            }
        }
    }
    out[idx] = acc;
}

extern "C" void kernel_launch(void* const* d_in, const int* in_sizes, int n_in,
                              void* d_out, int out_size, void* d_ws, size_t ws_size,
                              hipStream_t stream) {
    const float* x = (const float*)d_in[0];
    const float* w = (const float*)d_in[1];
    const float* fk = (const float*)d_in[2];
    float* out = (float*)d_out;

    const size_t ybytes = (size_t)NI * 10 * HY2 * 32 * 2;     // 43,264,000
    const size_t wtoff = ybytes;
    const size_t need = wtoff + (size_t)9 * CCH * CCH * 2;    // 45,107,200

    if (ws_size >= need) {
        __hip_bfloat16* yt = (__hip_bfloat16*)d_ws;
        __hip_bfloat16* wt = (__hip_bfloat16*)((char*)d_ws + wtoff);
        fir_kernel<<<16 * 17 * 20, 256, 0, stream>>>(x, fk, yt);
        wt2_kernel<<<(9 * CCH * CCH + 255) / 256, 256, 0, stream>>>(w, wt);
        conv_kernel<<<16 * 5 * 16, 256, 0, stream>>>(yt, wt, out);
    } else {
        naive_kernel<<<(NI * CCH * 32 * 32 + 255) / 256, 256, 0, stream>>>(x, w, fk, out);
    }
}

// Round 20
// 76.133 us; speedup vs baseline: 1.0501x; 1.0501x over previous
//
#include <hip/hip_runtime.h>
#include <hip/hip_bf16.h>

// FirDownsample: y = depthwise FIR(4x4 separable [1,3,3,1]) on x (pad 2),
// out = conv3x3(y, w), stride 2.  x:(16,320,64,64) f32, out:(16,320,32,32) f32.
//
// R20 = byte-exact R13 (best measured: 76.1us). fir = 8-row-band bf16-vlds
// (48us, at the transpose DRAM-efficiency wall: reads 2.5KB-contiguous per
// 16KB-strided plane, writes full 64B lines -- the balanced point; 7 structural
// variants all land 2.0-2.4 TB/s). conv = 4-wave M64xN16 (23us, ~63% of the
// 16x16-MFMA shape ceiling). wt2 4us.
//   K1 fir_kernel : x -> y[n][cc=10][65][65][32ci] bf16
//   K2 wt2_kernel : w -> wt2[tap][cc][q][co][8ci] bf16
//   K3 conv_kernel: M64xN64 block, 4 waves M64xN16, B reg-dbuf, A via global_load_lds.

typedef short bf16x8_t __attribute__((ext_vector_type(8)));
typedef float f32x4 __attribute__((ext_vector_type(4)));
typedef unsigned int u32x4 __attribute__((ext_vector_type(4)));
typedef __attribute__((address_space(1))) const unsigned int* as1_u32p;
typedef __attribute__((address_space(3))) unsigned int* as3_u32p;

#define NI 16
#define CCH 320
#define HW 64
#define HY 65
#define HY2 4225           // 65*65
#define CCSTEP 135200      // 4225*32 shorts per cc-plane

// ---------------- K1: separable FIR, x(f32) -> y bf16 [n][cc][r][c][32] ----------------
// block = (n, 8-row band, cc). vert: vlds[j8][ci32][70] bf16 (35.8KB -> 4 blocks/CU).
// horiz: task = (j, c-pair, octet s): 5 reads -> 2 outputs; paired 16B stores.
__global__ __launch_bounds__(256) void fir_kernel(const float* __restrict__ x,
                                                  const float* __restrict__ fir_k,
                                                  __hip_bfloat16* __restrict__ yt) {
    __shared__ unsigned short vlds[8 * 32 * 70];  // [j][ci][cc70] bf16 : 35,840 B
    int bx = blockIdx.x;
    int n    = bx / 90;
    int rem  = bx % 90;
    int band = rem / 10;          // 0..8
    int cc   = rem % 10;
    int r0   = band * 8;

    float f0 = fir_k[0] + fir_k[1] + fir_k[2] + fir_k[3];
    float f1 = fir_k[4] + fir_k[5] + fir_k[6] + fir_k[7];
    float f2 = fir_k[8] + fir_k[9] + fir_k[10] + fir_k[11];
    float f3 = fir_k[12] + fir_k[13] + fir_k[14] + fir_k[15];

    int tid = threadIdx.x;
    int lane = tid & 63;   // = w (vert)
    int g = tid >> 6;      // wave id

    // vertical pass: vlds[j][cis][w+2] = bf16( sum_a f[a] * x[r0+j-2+a][w] )
    for (int cis = g; cis < 32; cis += 4) {
        int ci = cc * 32 + cis;
        const float* xb = x + (size_t)(n * CCH + ci) * HW * HW;
        float xr[11];
#pragma unroll
        for (int t = 0; t < 11; ++t) {
            int row = r0 + t - 2;
            xr[t] = (row >= 0 && row < HW) ? xb[row * HW + lane] : 0.f;
        }
#pragma unroll
        for (int j = 0; j < 8; ++j) {
            float v = f0 * xr[j] + f1 * xr[j + 1] + f2 * xr[j + 2] + f3 * xr[j + 3];
            unsigned short* vrow = vlds + (j * 32 + cis) * 70;
            vrow[lane + 2] = __bfloat16_as_ushort(__float2bfloat16(v));
            if (lane < 2)   vrow[lane] = 0;         // cc 0,1
            if (lane >= 62) vrow[lane + 4] = 0;     // cc 66,67
        }
    }
    __syncthreads();

    // horizontal pass: task = (j, pair pp, octet s); 1056 tasks (8j x 33pp x 4s)
    unsigned short* yu = (unsigned short*)yt;
    size_t plane = (size_t)(n * 10 + cc) * HY2;
#pragma unroll
    for (int it = 0; it < 5; ++it) {
        int task = it * 256 + tid;
        if (task < 1056) {
            int s  = task & 3;
            int t2 = task >> 2;          // 0..263
            int j  = t2 / 33;
            int pp = t2 % 33;
            int c  = 2 * pp;
            int r  = r0 + j;
            if (r < HY) {
                const unsigned short* vb = vlds + (j * 32 + s * 8) * 70 + c;
                bool pair = (pp < 32);
                float a0[8], a1[8];
#pragma unroll
                for (int k = 0; k < 8; ++k) {
                    const unsigned short* vr = vb + k * 70;
                    float v0 = __bfloat162float(__ushort_as_bfloat16(vr[0]));
                    float v1 = __bfloat162float(__ushort_as_bfloat16(vr[1]));
                    float v2 = __bfloat162float(__ushort_as_bfloat16(vr[2]));
                    float v3 = __bfloat162float(__ushort_as_bfloat16(vr[3]));
                    a0[k] = f0 * v0 + f1 * v1 + f2 * v2 + f3 * v3;
                    if (pair) {
                        float v4 = __bfloat162float(__ushort_as_bfloat16(vr[4]));
                        a1[k] = f0 * v1 + f1 * v2 + f2 * v3 + f3 * v4;
                    }
                }
                unsigned int w0[4];
#pragma unroll
                for (int h = 0; h < 4; ++h) {
                    unsigned int lo = __bfloat16_as_ushort(__float2bfloat16(a0[2 * h]));
                    unsigned int hi = __bfloat16_as_ushort(__float2bfloat16(a0[2 * h + 1]));
                    w0[h] = lo | (hi << 16);
                }
                size_t base = (plane + (size_t)r * HY + c) * 32 + s * 8;
                *(u32x4*)(yu + base) = (u32x4){w0[0], w0[1], w0[2], w0[3]};
                if (pair) {
                    unsigned int w1[4];
#pragma unroll
                    for (int h = 0; h < 4; ++h) {
                        unsigned int lo = __bfloat16_as_ushort(__float2bfloat16(a1[2 * h]));
                        unsigned int hi = __bfloat16_as_ushort(__float2bfloat16(a1[2 * h + 1]));
                        w1[h] = lo | (hi << 16);
                    }
                    *(u32x4*)(yu + base + 32) = (u32x4){w1[0], w1[1], w1[2], w1[3]};
                }
            }
        }
    }
}

// ---------------- K2: w (co,ci,3,3) f32 -> wt2[tap][cc][q][co][8] bf16 ----------------
__global__ __launch_bounds__(256) void wt2_kernel(const float* __restrict__ w,
                                                  __hip_bfloat16* __restrict__ wt) {
    int idx = blockIdx.x * 256 + threadIdx.x;
    if (idx < 9 * CCH * CCH) {
        int j  = idx & 7;
        int co = (idx >> 3) % CCH;
        int t2 = idx / 2560;          // tap*40 + cc*4 + q
        int q  = t2 & 3;
        int cc = (t2 >> 2) % 10;
        int tap = t2 / 40;
        int ci = cc * 32 + q * 8 + j;
        wt[idx] = __float2bfloat16(w[(co * CCH + ci) * 9 + tap]);
    }
}

// ---------------- K3: MFMA conv, M64 x N64, waves M64xN16, B reg-dbuf (exact R10) ----------------
// grid = (n*5 + cb)*16 + sp ; wave wid owns co chunk wid*16.
// LDS: dbuf of 1536 16B-units; pos p = units 5p..5p+3 (+1 pad) -> 80B row pitch,
// conflict-free b128 reads. A staged via global_load_lds width 16.
__global__ __launch_bounds__(256, 3) void conv_kernel(const __hip_bfloat16* __restrict__ yt,
                                                      const __hip_bfloat16* __restrict__ wt2,
                                                      float* __restrict__ out) {
    __shared__ short ylds[2][1536 * 8];   // 2 x 24,576 B

    int bx = blockIdx.x;
    int sp = bx & 15;
    int t  = bx >> 4;
    int cb = t % 5;
    int n  = t / 5;
    int co0 = cb * 64;
    int oh0 = (sp >> 1) * 4;
    int ow0 = (sp & 1) * 16;

    int tid = threadIdx.x;
    int lane = tid & 63;
    int wid = tid >> 6;
    int q = lane >> 4, lc = lane & 15;

    const unsigned short* ytu = (const unsigned short*)yt;
    const unsigned short* wtu = (const unsigned short*)wt2;

    // per-lane global source offsets (shorts) for staging units, cc=0
    int ybase = (n * 10 * HY2 + (2 * oh0) * HY + 2 * ow0) * 32;
    int goff[6];
#pragma unroll
    for (int k = 0; k < 6; ++k) {
        int u = k * 256 + tid;
        int uc = (u < 1485) ? u : 1484;    // tail: safe dup, lands in pad units
        int p = uc / 5, s = uc - p * 5;
        if (s == 4) s = 3;                 // row-pad unit: dup of unit 3, never read
        int pr = p / 33, pc = p - pr * 33;
        goff[k] = ybase + (pr * HY + pc) * 32 + s * 8;
    }

    const unsigned short* wbl = wtu + q * 2560 + (size_t)(co0 + wid * 16 + lc) * 8;
    const int aoff = (2 * lc) * 40 + q * 8;   // short-index within buffer

    f32x4 acc[4];
#pragma unroll
    for (int i = 0; i < 4; ++i) acc[i] = (f32x4){0.f, 0.f, 0.f, 0.f};

    bf16x8_t bfr[2][9];

    // wave-uniform LDS unit base for stage issue k: (k*256 + wid*64) units
#define GLDS(buf, K, ccidx)                                                            \
    __builtin_amdgcn_global_load_lds(                                                  \
        (as1_u32p)(ytu + goff[K] + (ccidx) * CCSTEP),                                  \
        (as3_u32p)(&ylds[buf][(size_t)((K) * 256 + wid * 64) * 8]), 16, 0, 0)

    // prologue: stage A(0) -> buf0, load B(0) -> bfr[0]
#pragma unroll
    for (int k = 0; k < 6; ++k) GLDS(0, k, 0);
#pragma unroll
    for (int kk = 0; kk < 9; ++kk)
        bfr[0][kk] = *(const bf16x8_t*)(wbl + kk * 102400);
    __syncthreads();

    auto compute = [&](const short* buf, const bf16x8_t* b) {
#pragma unroll
        for (int kw = 0; kw < 3; ++kw) {
            bf16x8_t af[9];
#pragma unroll
            for (int r = 0; r < 9; ++r)
                af[r] = *(const bf16x8_t*)(buf + aoff + (r * 33 + kw) * 40);
#pragma unroll
            for (int kh = 0; kh < 3; ++kh)
#pragma unroll
                for (int mf = 0; mf < 4; ++mf)
                    acc[mf] = __builtin_amdgcn_mfma_f32_16x16x32_bf16(
                        b[kh * 3 + kw], af[2 * mf + kh], acc[mf], 0, 0, 0);
        }
    };

    for (int tt = 0; tt < 5; ++tt) {
        int cc0 = 2 * tt, cc1 = 2 * tt + 1;
        // ---- even cc: compute from buf0/bfr[0]; prefetch cc0+1 -> buf1/bfr[1]
        {
#pragma unroll
            for (int k = 0; k < 6; ++k) GLDS(1, k, cc0 + 1);
            const unsigned short* wnx = wbl + (cc0 + 1) * 10240;
#pragma unroll
            for (int kk = 0; kk < 9; ++kk)
                bfr[1][kk] = *(const bf16x8_t*)(wnx + kk * 102400);
            compute(&ylds[0][0], bfr[0]);
            __syncthreads();   // drains vmcnt -> A(cc0+1) in LDS, bfr[1] ready
        }
        // ---- odd cc: compute from buf1/bfr[1]; prefetch cc1+1 -> buf0/bfr[0]
        {
            if (cc1 < 9) {
#pragma unroll
                for (int k = 0; k < 6; ++k) GLDS(0, k, cc1 + 1);
                const unsigned short* wnx = wbl + (cc1 + 1) * 10240;
#pragma unroll
                for (int kk = 0; kk < 9; ++kk)
                    bfr[0][kk] = *(const bf16x8_t*)(wnx + kk * 102400);
            }
            compute(&ylds[1][0], bfr[1]);
            if (cc1 < 9) __syncthreads();
        }
    }
#undef GLDS

    // epilogue: D[row=co][col=m]; coalesced 64B segments
#pragma unroll
    for (int mf = 0; mf < 4; ++mf) {
        int oh = oh0 + mf;
        int ow = ow0 + lc;
#pragma unroll
        for (int rg = 0; rg < 4; ++rg) {
            int co = co0 + wid * 16 + q * 4 + rg;
            out[((n * CCH + co) * 32 + oh) * 32 + ow] = acc[mf][rg];
        }
    }
}

// ---------------- Fallback: naive direct (correct, slow) ----------------
__global__ __launch_bounds__(256) void naive_kernel(const float* __restrict__ x,
                                                    const float* __restrict__ w,
                                                    const float* __restrict__ fk,
                                                    float* __restrict__ out) {
    int idx = blockIdx.x * 256 + threadIdx.x;
    if (idx >= NI * CCH * 32 * 32) return;
    int ow = idx & 31;
    int oh = (idx >> 5) & 31;
    int co = (idx >> 10) % CCH;
    int n = (idx >> 10) / CCH;
    float f0 = fk[0] + fk[1] + fk[2] + fk[3];
    float f1 = fk[4] + fk[5] + fk[6] + fk[7];
    float f2 = fk[8] + fk[9] + fk[10] + fk[11];
    float f3 = fk[12] + fk[13] + fk[14] + fk[15];
    float fv[4] = {f0, f1, f2, f3};
    float acc = 0.f;
    for (int ci = 0; ci < CCH; ++ci) {
        const float* xb = x + (size_t)(n * CCH + ci) * HW * HW;
        const float* wb = w + (size_t)(co * CCH + ci) * 9;
#pragma unroll
        for (int u = 0; u < 3; ++u) {
            int yr = 2 * oh + u;
#pragma unroll
            for (int v = 0; v < 3; ++v) {
                int yc = 2 * ow + v;
                float s = 0.f;
#pragma unroll
                for (int a = 0; a < 4; ++a) {
                    int xrw = yr - 2 + a;
                    if (xrw < 0 || xrw >= HW) continue;
                    float t = 0.f;
#pragma unroll
                    for (int b = 0; b < 4; ++b) {
                        int xc = yc - 2 + b;
                        if (xc >= 0 && xc < HW) t += fv[b] * xb[xrw * HW + xc];
                    }
                    s += fv[a] * t;
                }
                acc += wb[u * 3 + v] * s;
            }
        }
    }
    out[idx] = acc;
}

extern "C" void kernel_launch(void* const* d_in, const int* in_sizes, int n_in,
                              void* d_out, int out_size, void* d_ws, size_t ws_size,
                              hipStream_t stream) {
    const float* x = (const float*)d_in[0];
    const float* w = (const float*)d_in[1];
    const float* fk = (const float*)d_in[2];
    float* out = (float*)d_out;

    const size_t ybytes = (size_t)NI * 10 * HY2 * 32 * 2;     // 43,264,000
    const size_t wtoff = ybytes;
    const size_t need = wtoff + (size_t)9 * CCH * CCH * 2;    // 45,107,200

    if (ws_size >= need) {
        __hip_bfloat16* yt = (__hip_bfloat16*)d_ws;
        __hip_bfloat16* wt = (__hip_bfloat16*)((char*)d_ws + wtoff);
        fir_kernel<<<16 * 9 * 10, 256, 0, stream>>>(x, fk, yt);
        wt2_kernel<<<(9 * CCH * CCH + 255) / 256, 256, 0, stream>>>(w, wt);
        conv_kernel<<<16 * 5 * 16, 256, 0, stream>>>(yt, wt, out);
    } else {
        naive_kernel<<<(NI * CCH * 32 * 32 + 255) / 256, 256, 0, stream>>>(x, w, fk, out);
    }
}